// Round 2
// baseline (513.065 us; speedup 1.0000x reference)
//
#include <hip/hip_runtime.h>
#include <hip/hip_bf16.h>

#define BATCH 16384
#define HDIM  512
#define BM    64
#define NT    1024

typedef float f32x4 __attribute__((ext_vector_type(4)));
typedef short s16x8 __attribute__((ext_vector_type(8)));

__device__ __forceinline__ unsigned short f2bf(float f) {
  unsigned u = __float_as_uint(f);
  u = (u + 0x7fffu + ((u >> 16) & 1u)) >> 16;  // round-to-nearest-even
  return (unsigned short)u;
}

// Convert W_i2h and W_h2h (each [1536,512] f32) to bf16 into d_ws.
// ws layout: [0 .. 786431] = Wx bf16, [786432 .. 1572863] = Wh bf16.
__global__ __launch_bounds__(256) void wconv_kernel(
    const float* __restrict__ wx, const float* __restrict__ wh,
    unsigned short* __restrict__ dst) {
  int i = blockIdx.x * 256 + threadIdx.x;  // float4 index, 0..393215
  const float4* src = (i < 196608) ? (const float4*)wx
                                   : ((const float4*)wh) - 196608;
  float4 v = src[i];
  ushort4 p;
  p.x = f2bf(v.x); p.y = f2bf(v.y); p.z = f2bf(v.z); p.w = f2bf(v.w);
  ((ushort4*)dst)[i] = p;
}

// Fused LayerNorm-GRU cell.
// Block: BM=64 rows x all 1536 gate-cols. 16 waves, wave w owns cols
// [w*32, w*32+32) of each gate group (r, z, n). Two K-phases:
//   phase X: A = x rows,  W = Wx(bf16): groups {r, z, xn}
//   phase H: A = h rows,  W = Wh(bf16): groups {r, z, hn}
// acc_r/acc_z accumulate across both phases (== x_g + h_g).
// A-tile double-buffered: h loads issued before KLOOP(x), LDS-written after
// (T14 issue-early/write-late; plain __syncthreads only).
__global__ __launch_bounds__(NT) void gru_fused_kernel(
    const float* __restrict__ x, const float* __restrict__ h,
    const unsigned short* __restrict__ Wxb, const unsigned short* __restrict__ Whb,
    const float* __restrict__ g_r, const float* __restrict__ b_r,
    const float* __restrict__ g_z, const float* __restrict__ b_z,
    const float* __restrict__ g_n, const float* __restrict__ b_n,
    float* __restrict__ out) {
  __shared__ __align__(16) unsigned short At[2][BM * 512];  // 2x64 KB, XOR-swizzled
  __shared__ float red[2][64][16][2];   // 16 KB: [slot][row][wave][sum,sumsq]
  __shared__ float rstat[2][64][2];     // [slot][row][mean,rstd]

  const int tid  = threadIdx.x;
  const int lane = tid & 63;
  const int w    = tid >> 6;    // wave 0..15
  const int l15  = lane & 15;
  const int lg   = lane >> 4;   // 0..3
  const int rowbase = blockIdx.x * BM;

  // B-fragment byte offsets: W row = g*512 + w*32 + cf*16 + l15, k-elem = lg*8
  int boff[3][2];
#pragma unroll
  for (int g = 0; g < 3; ++g)
#pragma unroll
    for (int cf = 0; cf < 2; ++cf)
      boff[g][cf] = ((g * 512 + w * 32 + cf * 16 + l15) * 512 + lg * 8) * 2;

  // per-lane gamma/beta for this lane's two columns
  const int c0 = w * 32 + l15, c1 = c0 + 16;
  float gr[2] = {g_r[c0], g_r[c1]}, brv[2] = {b_r[c0], b_r[c1]};
  float gz[2] = {g_z[c0], g_z[c1]}, bzv[2] = {b_z[c0], b_z[c1]};
  float gn[2] = {g_n[c0], g_n[c1]}, bnv[2] = {b_n[c0], b_n[c1]};

  f32x4 ar[4][2], az[4][2], axn[4][2], ahn[4][2];
#pragma unroll
  for (int rf = 0; rf < 4; ++rf)
#pragma unroll
    for (int cf = 0; cf < 2; ++cf) {
      ar[rf][cf] = (f32x4){0.f, 0.f, 0.f, 0.f};
      az[rf][cf] = (f32x4){0.f, 0.f, 0.f, 0.f};
      axn[rf][cf] = (f32x4){0.f, 0.f, 0.f, 0.f};
      ahn[rf][cf] = (f32x4){0.f, 0.f, 0.f, 0.f};
    }

  const int sr  = tid >> 7;   // staging row-within-group 0..7
  const int sc4 = tid & 127;  // staging float4 col 0..127

  // stage 64 rows x 512 cols of f32 src into At[buf] as bf16, swizzled
  auto stage = [&](const float* __restrict__ src, unsigned short* __restrict__ dst) {
    const float4* s4 = (const float4*)src;
#pragma unroll
    for (int p = 0; p < 8; ++p) {
      int r = p * 8 + sr;
      float4 v = s4[(rowbase + r) * 128 + sc4];
      ushort4 pk;
      pk.x = f2bf(v.x); pk.y = f2bf(v.y); pk.z = f2bf(v.z); pk.w = f2bf(v.w);
      int bo = (r * 1024 + sc4 * 8) ^ ((r & 7) << 4);
      *(ushort4*)((char*)dst + bo) = pk;
    }
  };

#define KLOOP(ATP, WPTR, ACCN)                                                 \
  _Pragma("unroll 2")                                                          \
  for (int kk = 0; kk < 16; ++kk) {                                            \
    s16x8 af[4];                                                               \
    _Pragma("unroll")                                                          \
    for (int rf = 0; rf < 4; ++rf) {                                           \
      int row = rf * 16 + l15;                                                 \
      int bo = (row * 1024 + kk * 64 + lg * 16) ^ ((row & 7) << 4);            \
      af[rf] = *(const s16x8*)((const char*)(ATP) + bo);                       \
    }                                                                          \
    s16x8 bfr[2], bfz[2], bfn[2];                                              \
    _Pragma("unroll")                                                          \
    for (int cf = 0; cf < 2; ++cf) {                                           \
      bfr[cf] = *(const s16x8*)((const char*)(WPTR) + boff[0][cf] + kk * 64);  \
      bfz[cf] = *(const s16x8*)((const char*)(WPTR) + boff[1][cf] + kk * 64);  \
      bfn[cf] = *(const s16x8*)((const char*)(WPTR) + boff[2][cf] + kk * 64);  \
    }                                                                          \
    _Pragma("unroll")                                                          \
    for (int rf = 0; rf < 4; ++rf)                                             \
      _Pragma("unroll")                                                        \
      for (int cf = 0; cf < 2; ++cf) {                                         \
        ar[rf][cf] = __builtin_amdgcn_mfma_f32_16x16x32_bf16(af[rf], bfr[cf], ar[rf][cf], 0, 0, 0); \
        az[rf][cf] = __builtin_amdgcn_mfma_f32_16x16x32_bf16(af[rf], bfz[cf], az[rf][cf], 0, 0, 0); \
        ACCN[rf][cf] = __builtin_amdgcn_mfma_f32_16x16x32_bf16(af[rf], bfn[cf], ACCN[rf][cf], 0, 0, 0); \
      }                                                                        \
  }

  stage(x, At[0]);
  __syncthreads();

  // issue h loads early — they stream in under KLOOP(x) (no barrier between
  // issue and use, so no forced vmcnt drain)
  float4 hv[8];
  {
    const float4* h4 = (const float4*)h;
#pragma unroll
    for (int p = 0; p < 8; ++p)
      hv[p] = h4[(rowbase + p * 8 + sr) * 128 + sc4];
  }

  KLOOP(At[0], Wxb, axn)

  // write-late: convert h regs -> At[1]
#pragma unroll
  for (int p = 0; p < 8; ++p) {
    int r = p * 8 + sr;
    ushort4 pk;
    pk.x = f2bf(hv[p].x); pk.y = f2bf(hv[p].y);
    pk.z = f2bf(hv[p].z); pk.w = f2bf(hv[p].w);
    int bo = (r * 1024 + sc4 * 8) ^ ((r & 7) << 4);
    *(ushort4*)((char*)At[1] + bo) = pk;
  }
  __syncthreads();

  KLOOP(At[1], Whb, ahn)

#define REDUCE(ACC, SLOT)                                                      \
  {                                                                            \
    _Pragma("unroll")                                                          \
    for (int rf = 0; rf < 4; ++rf) {                                           \
      _Pragma("unroll")                                                        \
      for (int rg = 0; rg < 4; ++rg) {                                         \
        float v0 = ACC[rf][0][rg], v1 = ACC[rf][1][rg];                        \
        float s = v0 + v1;                                                     \
        float q = v0 * v0 + v1 * v1;                                           \
        s += __shfl_xor(s, 1); q += __shfl_xor(q, 1);                          \
        s += __shfl_xor(s, 2); q += __shfl_xor(q, 2);                          \
        s += __shfl_xor(s, 4); q += __shfl_xor(q, 4);                          \
        s += __shfl_xor(s, 8); q += __shfl_xor(q, 8);                          \
        if (l15 == 0) {                                                        \
          int row = rf * 16 + lg * 4 + rg;                                     \
          red[SLOT][row][w][0] = s;                                            \
          red[SLOT][row][w][1] = q;                                            \
        }                                                                      \
      }                                                                        \
    }                                                                          \
  }

#define STATS(NG)                                                              \
  __syncthreads();                                                             \
  if (tid < 64 * (NG)) {                                                       \
    int slot = tid >> 6, row = tid & 63;                                       \
    float s = 0.f, q = 0.f;                                                    \
    _Pragma("unroll")                                                          \
    for (int ww = 0; ww < 16; ++ww) {                                          \
      s += red[slot][row][ww][0];                                              \
      q += red[slot][row][ww][1];                                              \
    }                                                                          \
    float mean = s * (1.0f / 512.0f);                                          \
    float var = q * (1.0f / 512.0f) - mean * mean;                             \
    rstat[slot][row][0] = mean;                                                \
    rstat[slot][row][1] = rsqrtf(var + 1e-5f);                                 \
  }                                                                            \
  __syncthreads();

  // --- LN + sigmoid for r and z; fold r into n-pre ---
  REDUCE(ar, 0)
  REDUCE(az, 1)
  STATS(2)

#pragma unroll
  for (int rf = 0; rf < 4; ++rf)
#pragma unroll
    for (int cf = 0; cf < 2; ++cf)
#pragma unroll
      for (int rg = 0; rg < 4; ++rg) {
        int row = rf * 16 + lg * 4 + rg;
        float m0 = rstat[0][row][0], s0 = rstat[0][row][1];
        float m1 = rstat[1][row][0], s1 = rstat[1][row][1];
        float rv = (ar[rf][cf][rg] - m0) * s0 * gr[cf] + brv[cf];
        rv = 1.0f / (1.0f + __expf(-rv));
        float zv = (az[rf][cf][rg] - m1) * s1 * gz[cf] + bzv[cf];
        az[rf][cf][rg] = 1.0f / (1.0f + __expf(-zv));
        axn[rf][cf][rg] += rv * ahn[rf][cf][rg];  // n_pre = x_n + r * h_n
      }

  // --- LN + tanh for n; combine ---
  REDUCE(axn, 0)
  STATS(1)

#pragma unroll
  for (int rf = 0; rf < 4; ++rf)
#pragma unroll
    for (int cf = 0; cf < 2; ++cf)
#pragma unroll
      for (int rg = 0; rg < 4; ++rg) {
        int row = rf * 16 + lg * 4 + rg;
        float m = rstat[0][row][0], sd = rstat[0][row][1];
        float arg = (axn[rf][cf][rg] - m) * sd * gn[cf] + bnv[cf];
        arg = fminf(fmaxf(arg, -20.f), 20.f);
        float e = __expf(2.0f * arg);
        float nv = (e - 1.0f) / (e + 1.0f);  // tanh
        int grow = rowbase + row;
        int gcol = w * 32 + cf * 16 + l15;
        float hval = h[(size_t)grow * 512 + gcol];
        float z = az[rf][cf][rg];
        out[(size_t)grow * 512 + gcol] = (1.0f - z) * nv + z * hval;
      }
}

extern "C" void kernel_launch(void* const* d_in, const int* in_sizes, int n_in,
                              void* d_out, int out_size, void* d_ws, size_t ws_size,
                              hipStream_t stream) {
  const float* x  = (const float*)d_in[0];
  const float* h  = (const float*)d_in[1];
  const float* wx = (const float*)d_in[2];
  const float* wh = (const float*)d_in[3];
  const float* g_r = (const float*)d_in[4];
  const float* b_r = (const float*)d_in[5];
  const float* g_z = (const float*)d_in[6];
  const float* b_z = (const float*)d_in[7];
  const float* g_n = (const float*)d_in[8];
  const float* b_n = (const float*)d_in[9];
  float* out = (float*)d_out;

  unsigned short* wbf = (unsigned short*)d_ws;  // 3 MB: Wx bf16 | Wh bf16

  wconv_kernel<<<1536, 256, 0, stream>>>(wx, wh, wbf);
  gru_fused_kernel<<<BATCH / BM, NT, 0, stream>>>(
      x, h, wbf, wbf + 1536 * 512, g_r, b_r, g_z, b_z, g_n, b_n, out);
}

// Round 5
// 233.623 us; speedup vs baseline: 2.1961x; 2.1961x over previous
//
#include <hip/hip_runtime.h>

#define BATCH 16384
#define BM    64
#define NT    1024

typedef float f32x4 __attribute__((ext_vector_type(4)));
typedef short s16x8 __attribute__((ext_vector_type(8)));

__device__ __forceinline__ unsigned short f2bf(float f) {
  unsigned u = __float_as_uint(f);
  u = (u + 0x7fffu + ((u >> 16) & 1u)) >> 16;  // round-to-nearest-even
  return (unsigned short)u;
}
__device__ __forceinline__ float bflo(unsigned p) { return __uint_as_float(p << 16); }
__device__ __forceinline__ float bfhi(unsigned p) { return __uint_as_float(p & 0xffff0000u); }

// Convert W_i2h and W_h2h (each [1536,512] f32) to bf16 into d_ws.
__global__ __launch_bounds__(256) void wconv_kernel(
    const float* __restrict__ wx, const float* __restrict__ wh,
    unsigned short* __restrict__ dst) {
  int i = blockIdx.x * 256 + threadIdx.x;  // float4 index, 0..393215
  const float4* src = (i < 196608) ? (const float4*)wx
                                   : ((const float4*)wh) - 196608;
  float4 v = src[i];
  ushort4 p = {f2bf(v.x), f2bf(v.y), f2bf(v.z), f2bf(v.w)};
  ((ushort4*)dst)[i] = p;
}

// Fused LayerNorm-GRU cell, gate-at-a-time to fit the 128-VGPR cap at
// 16 waves/CU (single-pass needed 128 acc regs alone -> 1.4 GB spill, R2).
// Block: BM=64 rows x all cols; 16 waves, wave w owns cols [w*32,w*32+32)
// of each gate. Both A-tiles (x,h bf16, XOR-swizzled) staged once in LDS;
// three passes r -> n -> z each keep only acc[4][2] (32 VGPR) live.
// n-pass: acc = h@Whn, acc *= r (MFMA C-in chaining), acc += x@Wxn.
__global__ __launch_bounds__(NT, 4) void gru_fused_kernel(
    const float* __restrict__ x, const float* __restrict__ h,
    const unsigned short* __restrict__ Wxb, const unsigned short* __restrict__ Whb,
    const float* __restrict__ g_r, const float* __restrict__ b_r,
    const float* __restrict__ g_z, const float* __restrict__ b_z,
    const float* __restrict__ g_n, const float* __restrict__ b_n,
    float* __restrict__ out) {
  __shared__ __align__(16) unsigned short At[2][BM * 512];  // 128 KB
  __shared__ float red[BM][33];   // stride-33: STATS reads 2-way, not 64-way
  __shared__ float rstat[BM][2];

  const int tid  = threadIdx.x;
  const int lane = tid & 63;
  const int w    = tid >> 6;    // wave 0..15
  const int l15  = lane & 15;
  const int lg   = lane >> 4;   // 0..3
  const int rowbase = blockIdx.x * BM;
  const int c0 = w * 32 + l15, c1 = c0 + 16;

  // ---- stage x -> At[0], h -> At[1] (bf16, XOR-swizzled) ----
  {
    const float4* x4 = (const float4*)x;
    const float4* h4 = (const float4*)h;
    const int sr = tid >> 7, sc4 = tid & 127;
#pragma unroll
    for (int p = 0; p < 8; ++p) {
      int r = p * 8 + sr;
      float4 vx = x4[(size_t)(rowbase + r) * 128 + sc4];
      float4 vh = h4[(size_t)(rowbase + r) * 128 + sc4];
      int bo = (r * 1024 + sc4 * 8) ^ ((r & 7) << 4);
      ushort4 px = {f2bf(vx.x), f2bf(vx.y), f2bf(vx.z), f2bf(vx.w)};
      ushort4 ph = {f2bf(vh.x), f2bf(vh.y), f2bf(vh.z), f2bf(vh.w)};
      *(ushort4*)((char*)At[0] + bo) = px;
      *(ushort4*)((char*)At[1] + bo) = ph;
    }
  }
  __syncthreads();

  f32x4 acc[4][2];

#define ZERO_ACC                                                               \
  _Pragma("unroll")                                                            \
  for (int rf = 0; rf < 4; ++rf)                                               \
    _Pragma("unroll")                                                          \
    for (int cf = 0; cf < 2; ++cf) acc[rf][cf] = (f32x4){0.f, 0.f, 0.f, 0.f};

#define KLOOP(ATP, WPTR, GBASE)                                                \
  {                                                                            \
    const char* wbase = (const char*)(WPTR);                                   \
    _Pragma("unroll 2")                                                        \
    for (int kk = 0; kk < 16; ++kk) {                                          \
      s16x8 af[4];                                                             \
      _Pragma("unroll")                                                        \
      for (int rf = 0; rf < 4; ++rf) {                                         \
        int row = rf * 16 + l15;                                               \
        int bo = (row * 1024 + kk * 64 + lg * 16) ^ ((row & 7) << 4);          \
        af[rf] = *(const s16x8*)((const char*)(ATP) + bo);                     \
      }                                                                        \
      s16x8 bf[2];                                                             \
      _Pragma("unroll")                                                        \
      for (int cf = 0; cf < 2; ++cf) {                                         \
        int wrow = (GBASE) + w * 32 + cf * 16 + l15;                           \
        bf[cf] = *(const s16x8*)(wbase + ((size_t)wrow * 512 + lg * 8) * 2 + kk * 64); \
      }                                                                        \
      _Pragma("unroll")                                                        \
      for (int rf = 0; rf < 4; ++rf)                                           \
        _Pragma("unroll")                                                      \
        for (int cf = 0; cf < 2; ++cf)                                         \
          acc[rf][cf] = __builtin_amdgcn_mfma_f32_16x16x32_bf16(af[rf], bf[cf], acc[rf][cf], 0, 0, 0); \
    }                                                                          \
  }

  // per-row sum/sumsq across the gate's 512 cols -> rstat[row] = {mean,rstd}
#define REDUCE_STATS                                                           \
  {                                                                            \
    _Pragma("unroll")                                                          \
    for (int rf = 0; rf < 4; ++rf) {                                           \
      _Pragma("unroll")                                                        \
      for (int rg = 0; rg < 4; ++rg) {                                         \
        float v0 = acc[rf][0][rg], v1 = acc[rf][1][rg];                        \
        float s = v0 + v1, q = v0 * v0 + v1 * v1;                              \
        s += __shfl_xor(s, 1); q += __shfl_xor(q, 1);                          \
        s += __shfl_xor(s, 2); q += __shfl_xor(q, 2);                          \
        s += __shfl_xor(s, 4); q += __shfl_xor(q, 4);                          \
        s += __shfl_xor(s, 8); q += __shfl_xor(q, 8);                          \
        if (l15 == 0) {                                                        \
          red[rf * 16 + lg * 4 + rg][w * 2]     = s;                           \
          red[rf * 16 + lg * 4 + rg][w * 2 + 1] = q;                           \
        }                                                                      \
      }                                                                        \
    }                                                                          \
    __syncthreads();                                                           \
    if (tid < 64) {                                                            \
      float s = 0.f, q = 0.f;                                                  \
      _Pragma("unroll")                                                        \
      for (int ww = 0; ww < 16; ++ww) {                                        \
        s += red[tid][ww * 2];                                                 \
        q += red[tid][ww * 2 + 1];                                             \
      }                                                                        \
      float mean = s * (1.0f / 512.0f);                                        \
      float var  = q * (1.0f / 512.0f) - mean * mean;                          \
      rstat[tid][0] = mean;                                                    \
      rstat[tid][1] = rsqrtf(var + 1e-5f);                                     \
    }                                                                          \
    __syncthreads();                                                           \
  }

  // ================= pass 1: r = sigmoid(LN(x_r + h_r)) =================
  ZERO_ACC
  KLOOP(At[0], Wxb, 0)
  KLOOP(At[1], Whb, 0)
  REDUCE_STATS

  unsigned rp[4][2][2];  // r packed bf16 pairs (error is LN-normalized later)
  {
    float ga[2] = {g_r[c0], g_r[c1]}, be[2] = {b_r[c0], b_r[c1]};
#pragma unroll
    for (int rf = 0; rf < 4; ++rf)
#pragma unroll
      for (int rg = 0; rg < 4; rg += 2) {
        int row0 = rf * 16 + lg * 4 + rg;
        float m0 = rstat[row0][0], s0 = rstat[row0][1];
        float m1 = rstat[row0 + 1][0], s1 = rstat[row0 + 1][1];
#pragma unroll
        for (int cf = 0; cf < 2; ++cf) {
          float r0 = (acc[rf][cf][rg] - m0) * s0 * ga[cf] + be[cf];
          float r1 = (acc[rf][cf][rg + 1] - m1) * s1 * ga[cf] + be[cf];
          r0 = 1.0f / (1.0f + __expf(-r0));
          r1 = 1.0f / (1.0f + __expf(-r1));
          rp[rf][cf][rg >> 1] = (unsigned)f2bf(r0) | ((unsigned)f2bf(r1) << 16);
        }
      }
  }

  // ============ pass 2: n = tanh(LN(x_n + r * h_n)) ============
  ZERO_ACC
  KLOOP(At[1], Whb, 1024)          // acc = h @ Whn^T
#pragma unroll
  for (int rf = 0; rf < 4; ++rf)
#pragma unroll
    for (int cf = 0; cf < 2; ++cf) {
      acc[rf][cf][0] *= bflo(rp[rf][cf][0]);
      acc[rf][cf][1] *= bfhi(rp[rf][cf][0]);
      acc[rf][cf][2] *= bflo(rp[rf][cf][1]);
      acc[rf][cf][3] *= bfhi(rp[rf][cf][1]);
    }
  KLOOP(At[0], Wxb, 1024)          // acc += x @ Wxn^T  (C-in chaining)
  REDUCE_STATS

  f32x4 nv[4][2];
  {
    float ga[2] = {g_n[c0], g_n[c1]}, be[2] = {b_n[c0], b_n[c1]};
#pragma unroll
    for (int rf = 0; rf < 4; ++rf)
#pragma unroll
      for (int rg = 0; rg < 4; ++rg) {
        int row = rf * 16 + lg * 4 + rg;
        float m = rstat[row][0], sd = rstat[row][1];
#pragma unroll
        for (int cf = 0; cf < 2; ++cf) {
          float arg = (acc[rf][cf][rg] - m) * sd * ga[cf] + be[cf];
          arg = fminf(fmaxf(arg, -20.f), 20.f);
          float e = __expf(2.0f * arg);
          nv[rf][cf][rg] = (e - 1.0f) / (e + 1.0f);  // tanh
        }
      }
  }

  // ====== pass 3: z = sigmoid(LN(x_z + h_z)); out = n + z*(h - n) ======
  ZERO_ACC
  KLOOP(At[0], Wxb, 512)
  KLOOP(At[1], Whb, 512)
  REDUCE_STATS

  {
    float ga[2] = {g_z[c0], g_z[c1]}, be[2] = {b_z[c0], b_z[c1]};
#pragma unroll
    for (int rf = 0; rf < 4; ++rf)
#pragma unroll
      for (int rg = 0; rg < 4; ++rg) {
        int row = rf * 16 + lg * 4 + rg;
        float m = rstat[row][0], sd = rstat[row][1];
        int grow = rowbase + row;
#pragma unroll
        for (int cf = 0; cf < 2; ++cf) {
          float zv = (acc[rf][cf][rg] - m) * sd * ga[cf] + be[cf];
          zv = 1.0f / (1.0f + __expf(-zv));
          int gcol = w * 32 + cf * 16 + l15;
          float hval = h[(size_t)grow * 512 + gcol];  // exact f32 h
          float n = nv[rf][cf][rg];
          out[(size_t)grow * 512 + gcol] = n + zv * (hval - n);
        }
      }
  }
}

extern "C" void kernel_launch(void* const* d_in, const int* in_sizes, int n_in,
                              void* d_out, int out_size, void* d_ws, size_t ws_size,
                              hipStream_t stream) {
  const float* x  = (const float*)d_in[0];
  const float* h  = (const float*)d_in[1];
  const float* wx = (const float*)d_in[2];
  const float* wh = (const float*)d_in[3];
  const float* g_r = (const float*)d_in[4];
  const float* b_r = (const float*)d_in[5];
  const float* g_z = (const float*)d_in[6];
  const float* b_z = (const float*)d_in[7];
  const float* g_n = (const float*)d_in[8];
  const float* b_n = (const float*)d_in[9];
  float* out = (float*)d_out;

  unsigned short* wbf = (unsigned short*)d_ws;  // 3 MB: Wx bf16 | Wh bf16

  wconv_kernel<<<1536, 256, 0, stream>>>(wx, wh, wbf);
  gru_fused_kernel<<<BATCH / BM, NT, 0, stream>>>(
      x, h, wbf, wbf + 1536 * 512, g_r, b_r, g_z, b_z, g_n, b_n, out);
}